// Round 10
// baseline (288.134 us; speedup 1.0000x reference)
//
#include <hip/hip_runtime.h>
#include <cstdint>
#include <cstddef>

#define N_TOK 4096
#define M_DIM 1024
#define APER  256
#define UNIF_START 3839   // rows >= this have no kept entries -> uniform 1/N

typedef __attribute__((ext_vector_type(8))) short short8;
typedef __attribute__((ext_vector_type(4))) float float4_t;

__device__ __forceinline__ unsigned short f2bf(float x) {
    union { float f; uint32_t u; } v; v.f = x;
    uint32_t u = v.u;
    u += 0x7FFFu + ((u >> 16) & 1u);   // round-to-nearest-even
    return (unsigned short)(u >> 16);
}

__device__ __forceinline__ float bf2f(unsigned short b) {
    union { uint32_t u; float f; } v; v.u = ((uint32_t)b) << 16;
    return v.f;
}

__device__ __forceinline__ void gload16(const void* g, void* l) {
    __builtin_amdgcn_global_load_lds(
        (const __attribute__((address_space(1))) void*)g,
        (__attribute__((address_space(3))) void*)l, 16, 0, 0);
}

// ---------------------------------------------------------------------------
// merged cast fp32 -> bf16 for x (4M elems) and WV (1M elems).
// ---------------------------------------------------------------------------
__global__ __launch_bounds__(256) void cast2(const float* __restrict__ x,
                                             unsigned short* __restrict__ xb,
                                             const float* __restrict__ WV,
                                             unsigned short* __restrict__ WVb) {
    const int i = (blockIdx.x * 256 + threadIdx.x) * 4;
    const float* src;
    unsigned short* dst;
    int off;
    if (i < N_TOK * M_DIM) { src = x;  dst = xb;  off = i; }
    else                   { src = WV; dst = WVb; off = i - N_TOK * M_DIM; }
    const float4 v = *reinterpret_cast<const float4*>(&src[off]);
    ushort4 o;
    o.x = f2bf(v.x); o.y = f2bf(v.y); o.z = f2bf(v.z); o.w = f2bf(v.w);
    *reinterpret_cast<ushort4*>(&dst[off]) = o;
}

// ---------------------------------------------------------------------------
// transpose+cast of 3 weight matrices (1024x1024 fp32 -> bf16^T)
// ---------------------------------------------------------------------------
__global__ __launch_bounds__(256) void wtrans3(const float* __restrict__ W0, const float* __restrict__ W1,
                                               const float* __restrict__ W2,
                                               unsigned short* __restrict__ D0, unsigned short* __restrict__ D1,
                                               unsigned short* __restrict__ D2) {
    const int z = blockIdx.z;
    const float* src = z == 0 ? W0 : (z == 1 ? W1 : W2);
    unsigned short* dst = z == 0 ? D0 : (z == 1 ? D1 : D2);
    __shared__ unsigned short tile[32][33];
    const int c0 = blockIdx.x * 32, r0 = blockIdx.y * 32;
    const int tx = threadIdx.x & 31, ty = threadIdx.x >> 5;
#pragma unroll
    for (int i = ty; i < 32; i += 8)
        tile[i][tx] = f2bf(src[(size_t)(r0 + i) * M_DIM + c0 + tx]);
    __syncthreads();
#pragma unroll
    for (int i = ty; i < 32; i += 8)
        dst[(size_t)(c0 + i) * M_DIM + r0 + tx] = tile[tx][i];
}

// transpose bf16 [R x C] -> bf16 [C x R]
__global__ __launch_bounds__(256) void transpose_bf16(const unsigned short* __restrict__ src,
                                                      unsigned short* __restrict__ dst,
                                                      int R, int C) {
    __shared__ unsigned short tile[32][33];
    const int c0 = blockIdx.x * 32, r0 = blockIdx.y * 32;
    const int tx = threadIdx.x & 31, ty = threadIdx.x >> 5;
#pragma unroll
    for (int i = ty; i < 32; i += 8)
        tile[i][tx] = src[(size_t)(r0 + i) * C + c0 + tx];
    __syncthreads();
#pragma unroll
    for (int i = ty; i < 32; i += 8)
        dst[(size_t)(c0 + i) * R + r0 + tx] = tile[tx][i];
}

// ---------------------------------------------------------------------------
// 64x64-tile NT GEMM (BK=32). Used only for the WVW^T fold.
// ---------------------------------------------------------------------------
__global__ __launch_bounds__(256) void nt64sq(const unsigned short* __restrict__ A,
                                              const unsigned short* __restrict__ B,
                                              unsigned short* __restrict__ Cb,
                                              int N, int K) {
    const int row0 = blockIdx.y * 64;
    const int col0 = blockIdx.x * 64;

    __shared__ unsigned short Asb[64 * 32];
    __shared__ unsigned short Bsb[64 * 32];

    const int t = threadIdx.x, w = t >> 6, lane = t & 63;
    float4_t acc[4] = {};

    const int sr   = lane >> 2;
    const int sk   = ((lane & 3) ^ ((sr >> 1) & 3)) * 8;
    const int m    = lane & 15;
    const int slot = ((lane >> 4) ^ ((m >> 1) & 3)) * 8;

    for (int k0 = 0; k0 < K; k0 += 32) {
        const int rr = w * 16 + sr;
        gload16(&A[(size_t)(row0 + rr) * K + k0 + sk], &Asb[w * 512]);
        gload16(&B[(size_t)(col0 + rr) * K + k0 + sk], &Bsb[w * 512]);
        __syncthreads();
        const short8 af = *reinterpret_cast<const short8*>(&Asb[(w * 16 + m) * 32 + slot]);
        short8 bf[4];
#pragma unroll
        for (int j = 0; j < 4; ++j)
            bf[j] = *reinterpret_cast<const short8*>(&Bsb[(j * 16 + m) * 32 + slot]);
#pragma unroll
        for (int j = 0; j < 4; ++j)
            acc[j] = __builtin_amdgcn_mfma_f32_16x16x32_bf16(af, bf[j], acc[j], 0, 0, 0);
        __syncthreads();
    }

    const int crow = row0 + w * 16 + (lane >> 4) * 4;
    const int ccol = col0 + m;
#pragma unroll
    for (int j = 0; j < 4; ++j)
#pragma unroll
        for (int r = 0; r < 4; ++r)
            Cb[(size_t)(crow + r) * N + ccol + j * 16] = f2bf(acc[j][r]);
}

// ---------------------------------------------------------------------------
// prep: blocks 0-3 compute svec (uniform-tail fold, 256 cols each);
// blocks 4-19 init rowsum (256 rows each).
// ---------------------------------------------------------------------------
__global__ __launch_bounds__(256) void prep_sr(const unsigned short* __restrict__ VWb,
                                               float* __restrict__ svec,
                                               float* __restrict__ rowsum) {
    const int bid = blockIdx.x;
    if (bid < 4) {
        const int c = bid * 256 + threadIdx.x;   // 0..1023
        float acc = 0.0f;
        for (int i = UNIF_START; i < N_TOK; ++i)
            acc += bf2f(VWb[(size_t)i * M_DIM + c]);
        svec[c] = acc * (1.0f / (float)N_TOK);
    } else {
        const int i = (bid - 4) * 256 + threadIdx.x;  // 0..4095
        rowsum[i] = (i >= UNIF_START) ? (float)N_TOK : 0.0f;
    }
}

// ---------------------------------------------------------------------------
// y[j,:] = s for rows 0..255 and 2048..4095 (rows 256..2047 are written
// directly by single-unit atv blocks). 64 + 512 = 576 blocks x 4 rows.
// ---------------------------------------------------------------------------
__global__ __launch_bounds__(256) void init_y(float* __restrict__ y, const float* __restrict__ s) {
    const float4 sv = reinterpret_cast<const float4*>(s)[threadIdx.x];
    const int bid = blockIdx.x;
    const int r0 = (bid < 64) ? bid * 4 : 2048 + (bid - 64) * 4;
#pragma unroll
    for (int r = 0; r < 4; ++r)
        reinterpret_cast<float4*>(&y[(size_t)(r0 + r) * M_DIM])[threadIdx.x] = sv;
}

// ---------------------------------------------------------------------------
// y += attT(kept) @ VW on the qkv-style 128x128 BK=32 core (R8-verified
// body). Tail folded: tile by (rows 128by..128by+127) has n = 4by-4 kept
// K-steps exactly (by 2..31); by 0,1 are pure svec (init_y).
// Units sorted DESCENDING by step count in a 46-entry table so the first
// 256 blocks (one per CU) are the largest; 112 small units backfill.
// by 2..15: single unit, direct y = acc + svec. by 16..31: two half-K
// units, atomicAdd onto init'd y (4.2M atomics, R7-proven level).
// Grid: 46 units * 8 x-cols = 368 blocks.
// ---------------------------------------------------------------------------
__global__ __launch_bounds__(256) void atv_bal(const unsigned short* __restrict__ A,
                                               const unsigned short* __restrict__ B,
                                               float* __restrict__ y,
                                               const float* __restrict__ svec) {
    // unit table sorted by descending ns; mode: 0=single, 1=half0, 2=half1
    static const unsigned char tby[46] = {
        31,31,30,30,29,29,15,28,28,27,27,14,26,26,25,25,13,24,24,23,23,12,
        22,22,21,21,11,20,20,19,19,10,18,18,17,17, 9,16,16, 8, 7, 6, 5, 4, 3, 2};
    static const unsigned char tmode[46] = {
        1,2,1,2,1,2,0,1,2,1,2,0,1,2,1,2,0,1,2,1,2,0,
        1,2,1,2,0,1,2,1,2,0,1,2,1,2,0,1,2,0,0,0,0,0,0,0};

    const int bid = (int)blockIdx.x;
    const int x   = bid & 7;
    const int uid = bid >> 3;                 // 0..45
    const int by   = tby[uid];
    const int mode = tmode[uid];
    int s0, ns;
    if (mode == 0)      { s0 = 0;           ns = 4 * by - 4; }
    else if (mode == 1) { s0 = 0;           ns = 2 * by - 2; }
    else                { s0 = 2 * by - 2;  ns = 2 * by - 2; }

    const int row0 = by * 128;          // y rows (attT rows)
    const int col0 = x * 128;           // y cols (VWt rows)

    __shared__ unsigned short Asb[128 * 32];
    __shared__ unsigned short Bsb[128 * 32];

    const int t = threadIdx.x, w = t >> 6, lane = t & 63;
    const int wr = (w >> 1) * 64, wc = (w & 1) * 64;

    float4_t acc[4][4] = {};

    const int sr   = lane >> 2;
    const int sk   = ((lane & 3) ^ ((sr >> 1) & 3)) * 8;
    const int m    = lane & 15;
    const int slot = ((lane >> 4) ^ ((m >> 1) & 3)) * 8;

    for (int s = 0; s < ns; ++s) {
        const int k0 = (s0 + s) * 32;
#pragma unroll
        for (int cc = 0; cc < 2; ++cc) {
            const int c = 2 * w + cc;
            const int rr = c * 16 + sr;
            gload16(&A[(size_t)(row0 + rr) * (size_t)N_TOK + k0 + sk], &Asb[c * 512]);
            gload16(&B[(size_t)(col0 + rr) * (size_t)N_TOK + k0 + sk], &Bsb[c * 512]);
        }
        __syncthreads();
        short8 af[4], bf[4];
#pragma unroll
        for (int i = 0; i < 4; ++i)
            af[i] = *reinterpret_cast<const short8*>(&Asb[(wr + i * 16 + m) * 32 + slot]);
#pragma unroll
        for (int j = 0; j < 4; ++j)
            bf[j] = *reinterpret_cast<const short8*>(&Bsb[(wc + j * 16 + m) * 32 + slot]);
#pragma unroll
        for (int i = 0; i < 4; ++i)
#pragma unroll
            for (int j = 0; j < 4; ++j)
                acc[i][j] = __builtin_amdgcn_mfma_f32_16x16x32_bf16(af[i], bf[j], acc[i][j], 0, 0, 0);
        __syncthreads();
    }

    const int crow = row0 + wr + (lane >> 4) * 4;
    const int ccol = col0 + wc + m;
    if (mode == 0) {
        float sv[4];
#pragma unroll
        for (int j = 0; j < 4; ++j) sv[j] = svec[ccol + j * 16];
#pragma unroll
        for (int i = 0; i < 4; ++i)
#pragma unroll
            for (int j = 0; j < 4; ++j)
#pragma unroll
                for (int r = 0; r < 4; ++r)
                    y[(size_t)(crow + i * 16 + r) * M_DIM + ccol + j * 16] =
                        acc[i][j][r] + sv[j];
    } else {
#pragma unroll
        for (int i = 0; i < 4; ++i)
#pragma unroll
            for (int j = 0; j < 4; ++j)
#pragma unroll
                for (int r = 0; r < 4; ++r)
                    atomicAdd(&y[(size_t)(crow + i * 16 + r) * M_DIM + ccol + j * 16],
                              acc[i][j][r]);
    }
}

// ---------------------------------------------------------------------------
// logits: Q @ K^T, 128x128 tile, BK=32 single-buffered core (R9-verified)
// over exactly the 465 active tiles (x >= y+2). Masked-exp epilogue +
// atomic rowsums.
// ---------------------------------------------------------------------------
__global__ __launch_bounds__(256) void logits_128(const unsigned short* __restrict__ A,
                                                  const unsigned short* __restrict__ B,
                                                  float* __restrict__ att,
                                                  float* __restrict__ rowsum) {
    // compact id -> (y,x) over { (y,x) : 0<=y<=29, y+2 <= x <= 31 }
    int rem = (int)blockIdx.x, y = 0;
    for (;;) {
        const int c = 30 - y;
        if (rem < c) break;
        rem -= c; ++y;
    }
    const int row0 = y * 128;
    const int col0 = (y + 2 + rem) * 128;

    __shared__ unsigned short Asb[128 * 32];
    __shared__ unsigned short Bsb[128 * 32];

    const int t = threadIdx.x, w = t >> 6, lane = t & 63;
    const int wr = (w >> 1) * 64, wc = (w & 1) * 64;

    float4_t acc[4][4] = {};

    const int sr   = lane >> 2;
    const int sk   = ((lane & 3) ^ ((sr >> 1) & 3)) * 8;
    const int m    = lane & 15;
    const int slot = ((lane >> 4) ^ ((m >> 1) & 3)) * 8;

    for (int k0 = 0; k0 < M_DIM; k0 += 32) {
#pragma unroll
        for (int cc = 0; cc < 2; ++cc) {
            const int c = 2 * w + cc;
            const int rr = c * 16 + sr;
            gload16(&A[(size_t)(row0 + rr) * M_DIM + k0 + sk], &Asb[c * 512]);
            gload16(&B[(size_t)(col0 + rr) * M_DIM + k0 + sk], &Bsb[c * 512]);
        }
        __syncthreads();
        short8 af[4], bf[4];
#pragma unroll
        for (int i = 0; i < 4; ++i)
            af[i] = *reinterpret_cast<const short8*>(&Asb[(wr + i * 16 + m) * 32 + slot]);
#pragma unroll
        for (int j = 0; j < 4; ++j)
            bf[j] = *reinterpret_cast<const short8*>(&Bsb[(wc + j * 16 + m) * 32 + slot]);
#pragma unroll
        for (int i = 0; i < 4; ++i)
#pragma unroll
            for (int j = 0; j < 4; ++j)
                acc[i][j] = __builtin_amdgcn_mfma_f32_16x16x32_bf16(af[i], bf[j], acc[i][j], 0, 0, 0);
        __syncthreads();
    }

    const int crow = row0 + wr + (lane >> 4) * 4;
    const int ccol = col0 + wc + m;
#pragma unroll
    for (int i = 0; i < 4; ++i) {
#pragma unroll
        for (int r = 0; r < 4; ++r) {
            const int gr = crow + i * 16 + r;
            float partial = 0.0f;
#pragma unroll
            for (int j = 0; j < 4; ++j) {
                const int gc = ccol + j * 16;
                float val;
                if (gr >= UNIF_START) {
                    val = 1.0f;
                } else if (gc > gr + APER) {
                    val = __expf(acc[i][j][r]);
                    partial += val;
                } else {
                    val = 0.0f;
                }
                att[(size_t)gr * N_TOK + gc] = val;
            }
            partial += __shfl_xor(partial, 1, 64);
            partial += __shfl_xor(partial, 2, 64);
            partial += __shfl_xor(partial, 4, 64);
            partial += __shfl_xor(partial, 8, 64);
            if (m == 0 && gr < UNIF_START) atomicAdd(&rowsum[gr], partial);
        }
    }
}

// ---------------------------------------------------------------------------
// Fused QKV (R4-proven BK=32 core): seg0 Kb, seg1 Qb (x0.06), seg2 VWb.
// ---------------------------------------------------------------------------
__global__ __launch_bounds__(256) void mfma_qkv(const unsigned short* __restrict__ xb,
                                                const unsigned short* __restrict__ WKt,
                                                const unsigned short* __restrict__ WQt,
                                                const unsigned short* __restrict__ WVWt,
                                                unsigned short* __restrict__ Kb,
                                                unsigned short* __restrict__ Qb,
                                                unsigned short* __restrict__ VWb) {
    const int row0  = blockIdx.y * 128;
    const int col0g = blockIdx.x * 128;
    const int seg   = col0g >> 10;
    const int col0  = col0g & 1023;
    const unsigned short* B = seg == 0 ? WKt : (seg == 1 ? WQt : WVWt);
    unsigned short*       C = seg == 0 ? Kb  : (seg == 1 ? Qb  : VWb);
    const float alpha = (seg == 1) ? 0.06f : 1.0f;

    __shared__ unsigned short Asb[128 * 32];
    __shared__ unsigned short Bsb[128 * 32];

    const int t = threadIdx.x, w = t >> 6, lane = t & 63;
    const int wr = (w >> 1) * 64, wc = (w & 1) * 64;

    float4_t acc[4][4] = {};

    const int sr   = lane >> 2;
    const int sk   = ((lane & 3) ^ ((sr >> 1) & 3)) * 8;
    const int m    = lane & 15;
    const int slot = ((lane >> 4) ^ ((m >> 1) & 3)) * 8;

    for (int k0 = 0; k0 < M_DIM; k0 += 32) {
#pragma unroll
        for (int cc = 0; cc < 2; ++cc) {
            const int c = 2 * w + cc;
            const int rr = c * 16 + sr;
            gload16(&xb[(size_t)(row0 + rr) * M_DIM + k0 + sk], &Asb[c * 512]);
            gload16(&B[(size_t)(col0 + rr) * M_DIM + k0 + sk], &Bsb[c * 512]);
        }
        __syncthreads();
        short8 af[4], bf[4];
#pragma unroll
        for (int i = 0; i < 4; ++i)
            af[i] = *reinterpret_cast<const short8*>(&Asb[(wr + i * 16 + m) * 32 + slot]);
#pragma unroll
        for (int j = 0; j < 4; ++j)
            bf[j] = *reinterpret_cast<const short8*>(&Bsb[(wc + j * 16 + m) * 32 + slot]);
#pragma unroll
        for (int i = 0; i < 4; ++i)
#pragma unroll
            for (int j = 0; j < 4; ++j)
                acc[i][j] = __builtin_amdgcn_mfma_f32_16x16x32_bf16(af[i], bf[j], acc[i][j], 0, 0, 0);
        __syncthreads();
    }

    const int crow = row0 + wr + (lane >> 4) * 4;
    const int ccol = col0 + wc + m;
#pragma unroll
    for (int i = 0; i < 4; ++i)
#pragma unroll
        for (int j = 0; j < 4; ++j)
#pragma unroll
            for (int r = 0; r < 4; ++r)
                C[(size_t)(crow + i * 16 + r) * M_DIM + ccol + j * 16] = f2bf(alpha * acc[i][j][r]);
}

// ---------------------------------------------------------------------------
// finalize: att = E * inv (in place, fp32) + attT = bf16(att)^T.
// attT entries for att-rows i >= UNIF_START are ZERO (folded into svec).
// ---------------------------------------------------------------------------
__global__ __launch_bounds__(256) void finalize_att(float* __restrict__ att,
                                                    unsigned short* __restrict__ attT,
                                                    const float* __restrict__ rowsum) {
    const int j0 = blockIdx.x * 64, i0 = blockIdx.y * 64;
    const int t = threadIdx.x;
    const int rl = t >> 4;             // 0..15
    const int c4 = (t & 15) * 4;       // 0,4,..,60
    const float u = 1.0f / (float)N_TOK;

    if (j0 + 63 <= i0 + APER) {        // trivial: att rows masked->0 / uniform->u
#pragma unroll
        for (int s = 0; s < 4; ++s) {
            const int i = i0 + rl + 16 * s;
            const float val = (i >= UNIF_START) ? u : 0.0f;
            float4 v; v.x = v.y = v.z = v.w = val;
            *reinterpret_cast<float4*>(&att[(size_t)i * N_TOK + j0 + c4]) = v;
        }
        const ushort4 z = {0, 0, 0, 0};
#pragma unroll
        for (int s = 0; s < 4; ++s) {
            const int j = j0 + rl + 16 * s;
            *reinterpret_cast<ushort4*>(&attT[(size_t)j * N_TOK + i0 + c4]) = z;
        }
        return;
    }

    __shared__ unsigned short tile[64][72];
#pragma unroll
    for (int s = 0; s < 4; ++s) {
        const int il = rl + 16 * s;
        const int i  = i0 + il;
        const float inv = 1.0f / rowsum[i];
        float4 v = *reinterpret_cast<const float4*>(&att[(size_t)i * N_TOK + j0 + c4]);
        v.x *= inv; v.y *= inv; v.z *= inv; v.w *= inv;
        *reinterpret_cast<float4*>(&att[(size_t)i * N_TOK + j0 + c4]) = v;
        ushort4 b;
        if (i >= UNIF_START) {
            b.x = b.y = b.z = b.w = 0;    // folded into svec
        } else {
            b.x = f2bf(v.x); b.y = f2bf(v.y); b.z = f2bf(v.z); b.w = f2bf(v.w);
        }
        *reinterpret_cast<ushort4*>(&tile[il][c4]) = b;
    }
    __syncthreads();
#pragma unroll
    for (int s = 0; s < 4; ++s) {
        const int jl = rl + 16 * s;
        ushort4 o;
        o.x = tile[c4 + 0][jl];
        o.y = tile[c4 + 1][jl];
        o.z = tile[c4 + 2][jl];
        o.w = tile[c4 + 3][jl];
        *reinterpret_cast<ushort4*>(&attT[(size_t)(j0 + jl) * N_TOK + i0 + c4]) = o;
    }
}

extern "C" void kernel_launch(void* const* d_in, const int* in_sizes, int n_in,
                              void* d_out, int out_size, void* d_ws, size_t ws_size,
                              hipStream_t stream) {
    const float* x    = (const float*)d_in[0];
    const float* WK   = (const float*)d_in[1];
    const float* WQ   = (const float*)d_in[2];
    const float* WV   = (const float*)d_in[3];
    const float* Wout = (const float*)d_in[4];

    float* y   = (float*)d_out;                  // 4096 x 1024 fp32
    float* att = y + (size_t)N_TOK * M_DIM;      // 4096 x 4096 fp32 (E, then normalized)

    // ws layout (ushort elements); 1 MEG = 2 MB
    unsigned short* base = (unsigned short*)d_ws;
    const size_t MEG = 1u << 20;
    unsigned short* xb    = base;             // [0,4)   x bf16; later VWt
    unsigned short* WKt   = base + 4  * MEG;  // [4,5)
    unsigned short* WQt   = base + 5  * MEG;  // [5,6)
    unsigned short* Woutt = base + 6  * MEG;  // [6,7)
    unsigned short* WVb   = base + 7  * MEG;  // [7,8)
    unsigned short* WVWt  = base + 8  * MEG;  // [8,9)
    unsigned short* Kb    = base + 9  * MEG;  // [9,13)
    unsigned short* Qb    = base + 13 * MEG;  // [13,17)
    unsigned short* VWb   = base + 17 * MEG;  // [17,21)
    unsigned short* attT  = base + 4  * MEG;  // [4,20) overlays dead wgt/Kb/Qb/VWb[0..3M)
    float*          rowsum = (float*)(base + 20 * MEG); // 16 KB (after VWb read)
    float*          svec   = (float*)(base + 20 * MEG) + 4096; // 4 KB s-vector
    unsigned short* VWt   = xb;               // [0,4) overlays dead xb

    const dim3 blk(256);

    // 1) input casts / transposes (merged x+WV cast)
    cast2<<<dim3((N_TOK * M_DIM + M_DIM * M_DIM) / 1024), blk, 0, stream>>>(x, xb, WV, WVb);
    wtrans3<<<dim3(M_DIM / 32, M_DIM / 32, 3), blk, 0, stream>>>(WK, WQ, Wout, WKt, WQt, Woutt);

    // 2) WVW^T = Wout^T @ WV^T  (folds Wout into the V projection)
    nt64sq<<<dim3(M_DIM / 64, M_DIM / 64), blk, 0, stream>>>(Woutt, WVb, WVWt, M_DIM, M_DIM);

    // 3) fused K/Q/VW projections
    mfma_qkv<<<dim3(24, N_TOK / 128), blk, 0, stream>>>(xb, WKt, WQt, WVWt, Kb, Qb, VWb);

    // 4) VW^T (xb region is dead now); svec + rowsum init; y base rows
    transpose_bf16<<<dim3(M_DIM / 32, N_TOK / 32), blk, 0, stream>>>(VWb, VWt, N_TOK, M_DIM);
    prep_sr<<<dim3(20), blk, 0, stream>>>(VWb, svec, rowsum);
    init_y<<<dim3(576), blk, 0, stream>>>(y, svec);

    // 5) logits -> masked exp E + row sums (compact 465-block grid, BK=32 core)
    logits_128<<<dim3(465), blk, 0, stream>>>(Qb, Kb, att, rowsum);

    // 6) normalize att in place + build attT (bf16, uniform rows zeroed), fused
    finalize_att<<<dim3(N_TOK / 64, N_TOK / 64), blk, 0, stream>>>(att, attT, rowsum);

    // 7) y += attT(kept) @ VW  (qkv-core, size-sorted units, <=2-way split)
    atv_bal<<<dim3(368), blk, 0, stream>>>(attT, VWt, y, svec);
}

// Round 11
// 268.748 us; speedup vs baseline: 1.0721x; 1.0721x over previous
//
#include <hip/hip_runtime.h>
#include <cstdint>
#include <cstddef>

#define N_TOK 4096
#define M_DIM 1024
#define APER  256
#define UNIF_START 3839   // rows >= this have no kept entries -> uniform 1/N

typedef __attribute__((ext_vector_type(8))) short short8;
typedef __attribute__((ext_vector_type(4))) float float4_t;

__device__ __forceinline__ unsigned short f2bf(float x) {
    union { float f; uint32_t u; } v; v.f = x;
    uint32_t u = v.u;
    u += 0x7FFFu + ((u >> 16) & 1u);   // round-to-nearest-even
    return (unsigned short)(u >> 16);
}

__device__ __forceinline__ float bf2f(unsigned short b) {
    union { uint32_t u; float f; } v; v.u = ((uint32_t)b) << 16;
    return v.f;
}

__device__ __forceinline__ void gload16(const void* g, void* l) {
    __builtin_amdgcn_global_load_lds(
        (const __attribute__((address_space(1))) void*)g,
        (__attribute__((address_space(3))) void*)l, 16, 0, 0);
}

// ---------------------------------------------------------------------------
// merged cast fp32 -> bf16 for x (4M elems) and WV (1M elems).
// ---------------------------------------------------------------------------
__global__ __launch_bounds__(256) void cast2(const float* __restrict__ x,
                                             unsigned short* __restrict__ xb,
                                             const float* __restrict__ WV,
                                             unsigned short* __restrict__ WVb) {
    const int i = (blockIdx.x * 256 + threadIdx.x) * 4;
    const float* src;
    unsigned short* dst;
    int off;
    if (i < N_TOK * M_DIM) { src = x;  dst = xb;  off = i; }
    else                   { src = WV; dst = WVb; off = i - N_TOK * M_DIM; }
    const float4 v = *reinterpret_cast<const float4*>(&src[off]);
    ushort4 o;
    o.x = f2bf(v.x); o.y = f2bf(v.y); o.z = f2bf(v.z); o.w = f2bf(v.w);
    *reinterpret_cast<ushort4*>(&dst[off]) = o;
}

// ---------------------------------------------------------------------------
// transpose+cast of 3 weight matrices (1024x1024 fp32 -> bf16^T)
// ---------------------------------------------------------------------------
__global__ __launch_bounds__(256) void wtrans3(const float* __restrict__ W0, const float* __restrict__ W1,
                                               const float* __restrict__ W2,
                                               unsigned short* __restrict__ D0, unsigned short* __restrict__ D1,
                                               unsigned short* __restrict__ D2) {
    const int z = blockIdx.z;
    const float* src = z == 0 ? W0 : (z == 1 ? W1 : W2);
    unsigned short* dst = z == 0 ? D0 : (z == 1 ? D1 : D2);
    __shared__ unsigned short tile[32][33];
    const int c0 = blockIdx.x * 32, r0 = blockIdx.y * 32;
    const int tx = threadIdx.x & 31, ty = threadIdx.x >> 5;
#pragma unroll
    for (int i = ty; i < 32; i += 8)
        tile[i][tx] = f2bf(src[(size_t)(r0 + i) * M_DIM + c0 + tx]);
    __syncthreads();
#pragma unroll
    for (int i = ty; i < 32; i += 8)
        dst[(size_t)(c0 + i) * M_DIM + r0 + tx] = tile[tx][i];
}

// transpose bf16 [R x C] -> bf16 [C x R]
__global__ __launch_bounds__(256) void transpose_bf16(const unsigned short* __restrict__ src,
                                                      unsigned short* __restrict__ dst,
                                                      int R, int C) {
    __shared__ unsigned short tile[32][33];
    const int c0 = blockIdx.x * 32, r0 = blockIdx.y * 32;
    const int tx = threadIdx.x & 31, ty = threadIdx.x >> 5;
#pragma unroll
    for (int i = ty; i < 32; i += 8)
        tile[i][tx] = src[(size_t)(r0 + i) * C + c0 + tx];
    __syncthreads();
#pragma unroll
    for (int i = ty; i < 32; i += 8)
        dst[(size_t)(c0 + i) * R + r0 + tx] = tile[tx][i];
}

// ---------------------------------------------------------------------------
// 64x64-tile NT GEMM (BK=32). Used only for the WVW^T fold.
// ---------------------------------------------------------------------------
__global__ __launch_bounds__(256) void nt64sq(const unsigned short* __restrict__ A,
                                              const unsigned short* __restrict__ B,
                                              unsigned short* __restrict__ Cb,
                                              int N, int K) {
    const int row0 = blockIdx.y * 64;
    const int col0 = blockIdx.x * 64;

    __shared__ unsigned short Asb[64 * 32];
    __shared__ unsigned short Bsb[64 * 32];

    const int t = threadIdx.x, w = t >> 6, lane = t & 63;
    float4_t acc[4] = {};

    const int sr   = lane >> 2;
    const int sk   = ((lane & 3) ^ ((sr >> 1) & 3)) * 8;
    const int m    = lane & 15;
    const int slot = ((lane >> 4) ^ ((m >> 1) & 3)) * 8;

    for (int k0 = 0; k0 < K; k0 += 32) {
        const int rr = w * 16 + sr;
        gload16(&A[(size_t)(row0 + rr) * K + k0 + sk], &Asb[w * 512]);
        gload16(&B[(size_t)(col0 + rr) * K + k0 + sk], &Bsb[w * 512]);
        __syncthreads();
        const short8 af = *reinterpret_cast<const short8*>(&Asb[(w * 16 + m) * 32 + slot]);
        short8 bf[4];
#pragma unroll
        for (int j = 0; j < 4; ++j)
            bf[j] = *reinterpret_cast<const short8*>(&Bsb[(j * 16 + m) * 32 + slot]);
#pragma unroll
        for (int j = 0; j < 4; ++j)
            acc[j] = __builtin_amdgcn_mfma_f32_16x16x32_bf16(af, bf[j], acc[j], 0, 0, 0);
        __syncthreads();
    }

    const int crow = row0 + w * 16 + (lane >> 4) * 4;
    const int ccol = col0 + m;
#pragma unroll
    for (int j = 0; j < 4; ++j)
#pragma unroll
        for (int r = 0; r < 4; ++r)
            Cb[(size_t)(crow + r) * N + ccol + j * 16] = f2bf(acc[j][r]);
}

// ---------------------------------------------------------------------------
// prep: blocks 0-3 compute svec (uniform-tail fold, 256 cols each);
// blocks 4-19 init rowsum (256 rows each).
// ---------------------------------------------------------------------------
__global__ __launch_bounds__(256) void prep_sr(const unsigned short* __restrict__ VWb,
                                               float* __restrict__ svec,
                                               float* __restrict__ rowsum) {
    const int bid = blockIdx.x;
    if (bid < 4) {
        const int c = bid * 256 + threadIdx.x;   // 0..1023
        float acc = 0.0f;
        for (int i = UNIF_START; i < N_TOK; ++i)
            acc += bf2f(VWb[(size_t)i * M_DIM + c]);
        svec[c] = acc * (1.0f / (float)N_TOK);
    } else {
        const int i = (bid - 4) * 256 + threadIdx.x;  // 0..4095
        rowsum[i] = (i >= UNIF_START) ? (float)N_TOK : 0.0f;
    }
}

// ---------------------------------------------------------------------------
// y[j,:] = s for rows 0..255 and 2304..4095 (rows 256..2303 are written
// directly by unsplit atv blocks). 64 + 448 = 512 blocks x 4 rows.
// ---------------------------------------------------------------------------
__global__ __launch_bounds__(256) void init_y(float* __restrict__ y, const float* __restrict__ s) {
    const float4 sv = reinterpret_cast<const float4*>(s)[threadIdx.x];
    const int bid = blockIdx.x;
    const int r0 = (bid < 64) ? bid * 4 : 2304 + (bid - 64) * 4;
#pragma unroll
    for (int r = 0; r < 4; ++r)
        reinterpret_cast<float4*>(&y[(size_t)(r0 + r) * M_DIM])[threadIdx.x] = sv;
}

// ---------------------------------------------------------------------------
// y += attT(kept) @ VW. 64x128 tile, BK=64, dbuf (R2 core), tail folded.
// by in [4,35]: single block, DIRECT store y = acc + svec (no atomics).
// by in [36,63]: two half-K blocks, atomicAdd onto init'd y.
// Grid: 8 x-cols * (32 singles + 56 halves) = 704 blocks. (R7/R9-verified.)
// ---------------------------------------------------------------------------
__global__ __launch_bounds__(256) void atv_split(const unsigned short* __restrict__ A,
                                                 const unsigned short* __restrict__ B,
                                                 float* __restrict__ y,
                                                 const float* __restrict__ svec) {
    const int bid  = (int)blockIdx.x;
    const int x    = bid & 7;
    const int unit = bid >> 3;
    int by, s0, ns, direct;
    if (unit < 32) {                    // by 4..35, whole K-range (1..32 steps)
        by = 4 + unit; s0 = 0; ns = by - 3; direct = 1;
    } else {                            // by 36..63, two halves (15..30 steps)
        const int v = unit - 32;
        by = 36 + (v >> 1);
        const int tot = by - 3;
        const int n1  = (tot + 1) >> 1;
        if (v & 1) { s0 = n1; ns = tot - n1; }
        else       { s0 = 0;  ns = n1; }
        direct = 0;
    }
    const int row0 = by * 64;           // y rows (attT rows)
    const int col0 = x * 128;           // y cols (VWt rows)

    __shared__ unsigned short As[2][64 * 64];    // 16 KB
    __shared__ unsigned short Bs[2][128 * 64];   // 32 KB

    const int t = threadIdx.x, w = t >> 6, lane = t & 63;
    const int wr = (w >> 1) * 32, wc = (w & 1) * 64;
    const int q = lane >> 4, m = lane & 15;

    const int srow = lane >> 3;                         // 0..7
    const int schk = ((lane & 7) ^ (srow & 7)) * 8;     // pre-swizzled global chunk

    int aoff[2][2], boff[4][2];
#pragma unroll
    for (int i = 0; i < 2; ++i)
#pragma unroll
        for (int h = 0; h < 2; ++h)
            aoff[i][h] = (wr + i * 16 + m) * 64 + (((h * 4 + q) ^ (m & 7)) * 8);
#pragma unroll
    for (int j = 0; j < 4; ++j)
#pragma unroll
        for (int h = 0; h < 2; ++h)
            boff[j][h] = (wc + j * 16 + m) * 64 + (((h * 4 + q) ^ (m & 7)) * 8);

    float4_t acc[2][4] = {};

    auto stage = [&](int buf, int s) {
        const int k0 = (s0 + s) * 64;
#pragma unroll
        for (int c = 0; c < 2; ++c) {         // A: 64 rows
            const int r0 = w * 16 + c * 8;
            gload16(&A[(size_t)(row0 + r0 + srow) * (size_t)N_TOK + k0 + schk],
                    &As[buf][r0 * 64]);
        }
#pragma unroll
        for (int c = 0; c < 4; ++c) {         // B: 128 rows
            const int r0 = w * 32 + c * 8;
            gload16(&B[(size_t)(col0 + r0 + srow) * (size_t)N_TOK + k0 + schk],
                    &Bs[buf][r0 * 64]);
        }
    };

    stage(0, 0);
    __syncthreads();

    int cur = 0;
    for (int s = 0; s < ns; ++s) {
        if (s + 1 < ns) stage(cur ^ 1, s + 1);
        short8 af[2][2], bf[4][2];
#pragma unroll
        for (int i = 0; i < 2; ++i)
#pragma unroll
            for (int h = 0; h < 2; ++h)
                af[i][h] = *reinterpret_cast<const short8*>(&As[cur][aoff[i][h]]);
#pragma unroll
        for (int j = 0; j < 4; ++j)
#pragma unroll
            for (int h = 0; h < 2; ++h)
                bf[j][h] = *reinterpret_cast<const short8*>(&Bs[cur][boff[j][h]]);
#pragma unroll
        for (int i = 0; i < 2; ++i)
#pragma unroll
            for (int j = 0; j < 4; ++j)
#pragma unroll
                for (int h = 0; h < 2; ++h)
                    acc[i][j] = __builtin_amdgcn_mfma_f32_16x16x32_bf16(af[i][h], bf[j][h],
                                                                        acc[i][j], 0, 0, 0);
        __syncthreads();
        cur ^= 1;
    }

    if (direct) {
        float sv[4];
#pragma unroll
        for (int j = 0; j < 4; ++j) sv[j] = svec[col0 + wc + j * 16 + m];
#pragma unroll
        for (int i = 0; i < 2; ++i)
#pragma unroll
            for (int j = 0; j < 4; ++j)
#pragma unroll
                for (int r = 0; r < 4; ++r)
                    y[(size_t)(row0 + wr + i * 16 + q * 4 + r) * M_DIM +
                      col0 + wc + j * 16 + m] = acc[i][j][r] + sv[j];
    } else {
#pragma unroll
        for (int i = 0; i < 2; ++i)
#pragma unroll
            for (int j = 0; j < 4; ++j)
#pragma unroll
                for (int r = 0; r < 4; ++r)
                    atomicAdd(&y[(size_t)(row0 + wr + i * 16 + q * 4 + r) * M_DIM +
                                 col0 + wc + j * 16 + m],
                              acc[i][j][r]);
    }
}

// ---------------------------------------------------------------------------
// logits: Q @ K^T, 128x128 tile, BK=32 single-buffered core (R9-verified)
// over exactly the 465 active tiles (x >= y+2). Masked-exp epilogue +
// atomic rowsums.
// ---------------------------------------------------------------------------
__global__ __launch_bounds__(256) void logits_128(const unsigned short* __restrict__ A,
                                                  const unsigned short* __restrict__ B,
                                                  float* __restrict__ att,
                                                  float* __restrict__ rowsum) {
    // compact id -> (y,x) over { (y,x) : 0<=y<=29, y+2 <= x <= 31 }
    int rem = (int)blockIdx.x, y = 0;
    for (;;) {
        const int c = 30 - y;
        if (rem < c) break;
        rem -= c; ++y;
    }
    const int row0 = y * 128;
    const int col0 = (y + 2 + rem) * 128;

    __shared__ unsigned short Asb[128 * 32];
    __shared__ unsigned short Bsb[128 * 32];

    const int t = threadIdx.x, w = t >> 6, lane = t & 63;
    const int wr = (w >> 1) * 64, wc = (w & 1) * 64;

    float4_t acc[4][4] = {};

    const int sr   = lane >> 2;
    const int sk   = ((lane & 3) ^ ((sr >> 1) & 3)) * 8;
    const int m    = lane & 15;
    const int slot = ((lane >> 4) ^ ((m >> 1) & 3)) * 8;

    for (int k0 = 0; k0 < M_DIM; k0 += 32) {
#pragma unroll
        for (int cc = 0; cc < 2; ++cc) {
            const int c = 2 * w + cc;
            const int rr = c * 16 + sr;
            gload16(&A[(size_t)(row0 + rr) * M_DIM + k0 + sk], &Asb[c * 512]);
            gload16(&B[(size_t)(col0 + rr) * M_DIM + k0 + sk], &Bsb[c * 512]);
        }
        __syncthreads();
        short8 af[4], bf[4];
#pragma unroll
        for (int i = 0; i < 4; ++i)
            af[i] = *reinterpret_cast<const short8*>(&Asb[(wr + i * 16 + m) * 32 + slot]);
#pragma unroll
        for (int j = 0; j < 4; ++j)
            bf[j] = *reinterpret_cast<const short8*>(&Bsb[(wc + j * 16 + m) * 32 + slot]);
#pragma unroll
        for (int i = 0; i < 4; ++i)
#pragma unroll
            for (int j = 0; j < 4; ++j)
                acc[i][j] = __builtin_amdgcn_mfma_f32_16x16x32_bf16(af[i], bf[j], acc[i][j], 0, 0, 0);
        __syncthreads();
    }

    const int crow = row0 + wr + (lane >> 4) * 4;
    const int ccol = col0 + wc + m;
#pragma unroll
    for (int i = 0; i < 4; ++i) {
#pragma unroll
        for (int r = 0; r < 4; ++r) {
            const int gr = crow + i * 16 + r;
            float partial = 0.0f;
#pragma unroll
            for (int j = 0; j < 4; ++j) {
                const int gc = ccol + j * 16;
                float val;
                if (gr >= UNIF_START) {
                    val = 1.0f;
                } else if (gc > gr + APER) {
                    val = __expf(acc[i][j][r]);
                    partial += val;
                } else {
                    val = 0.0f;
                }
                att[(size_t)gr * N_TOK + gc] = val;
            }
            partial += __shfl_xor(partial, 1, 64);
            partial += __shfl_xor(partial, 2, 64);
            partial += __shfl_xor(partial, 4, 64);
            partial += __shfl_xor(partial, 8, 64);
            if (m == 0 && gr < UNIF_START) atomicAdd(&rowsum[gr], partial);
        }
    }
}

// ---------------------------------------------------------------------------
// Fused QKV (R4-proven BK=32 core): seg0 Kb, seg1 Qb (x0.06), seg2 VWb.
// ---------------------------------------------------------------------------
__global__ __launch_bounds__(256) void mfma_qkv(const unsigned short* __restrict__ xb,
                                                const unsigned short* __restrict__ WKt,
                                                const unsigned short* __restrict__ WQt,
                                                const unsigned short* __restrict__ WVWt,
                                                unsigned short* __restrict__ Kb,
                                                unsigned short* __restrict__ Qb,
                                                unsigned short* __restrict__ VWb) {
    const int row0  = blockIdx.y * 128;
    const int col0g = blockIdx.x * 128;
    const int seg   = col0g >> 10;
    const int col0  = col0g & 1023;
    const unsigned short* B = seg == 0 ? WKt : (seg == 1 ? WQt : WVWt);
    unsigned short*       C = seg == 0 ? Kb  : (seg == 1 ? Qb  : VWb);
    const float alpha = (seg == 1) ? 0.06f : 1.0f;

    __shared__ unsigned short Asb[128 * 32];
    __shared__ unsigned short Bsb[128 * 32];

    const int t = threadIdx.x, w = t >> 6, lane = t & 63;
    const int wr = (w >> 1) * 64, wc = (w & 1) * 64;

    float4_t acc[4][4] = {};

    const int sr   = lane >> 2;
    const int sk   = ((lane & 3) ^ ((sr >> 1) & 3)) * 8;
    const int m    = lane & 15;
    const int slot = ((lane >> 4) ^ ((m >> 1) & 3)) * 8;

    for (int k0 = 0; k0 < M_DIM; k0 += 32) {
#pragma unroll
        for (int cc = 0; cc < 2; ++cc) {
            const int c = 2 * w + cc;
            const int rr = c * 16 + sr;
            gload16(&xb[(size_t)(row0 + rr) * M_DIM + k0 + sk], &Asb[c * 512]);
            gload16(&B[(size_t)(col0 + rr) * M_DIM + k0 + sk], &Bsb[c * 512]);
        }
        __syncthreads();
        short8 af[4], bf[4];
#pragma unroll
        for (int i = 0; i < 4; ++i)
            af[i] = *reinterpret_cast<const short8*>(&Asb[(wr + i * 16 + m) * 32 + slot]);
#pragma unroll
        for (int j = 0; j < 4; ++j)
            bf[j] = *reinterpret_cast<const short8*>(&Bsb[(wc + j * 16 + m) * 32 + slot]);
#pragma unroll
        for (int i = 0; i < 4; ++i)
#pragma unroll
            for (int j = 0; j < 4; ++j)
                acc[i][j] = __builtin_amdgcn_mfma_f32_16x16x32_bf16(af[i], bf[j], acc[i][j], 0, 0, 0);
        __syncthreads();
    }

    const int crow = row0 + wr + (lane >> 4) * 4;
    const int ccol = col0 + wc + m;
#pragma unroll
    for (int i = 0; i < 4; ++i)
#pragma unroll
        for (int j = 0; j < 4; ++j)
#pragma unroll
            for (int r = 0; r < 4; ++r)
                C[(size_t)(crow + i * 16 + r) * M_DIM + ccol + j * 16] = f2bf(alpha * acc[i][j][r]);
}

// ---------------------------------------------------------------------------
// finalize: att = E * inv (in place, fp32) + attT = bf16(att)^T.
// attT entries for att-rows i >= UNIF_START are ZERO (folded into svec).
// ---------------------------------------------------------------------------
__global__ __launch_bounds__(256) void finalize_att(float* __restrict__ att,
                                                    unsigned short* __restrict__ attT,
                                                    const float* __restrict__ rowsum) {
    const int j0 = blockIdx.x * 64, i0 = blockIdx.y * 64;
    const int t = threadIdx.x;
    const int rl = t >> 4;             // 0..15
    const int c4 = (t & 15) * 4;       // 0,4,..,60
    const float u = 1.0f / (float)N_TOK;

    if (j0 + 63 <= i0 + APER) {        // trivial: att rows masked->0 / uniform->u
#pragma unroll
        for (int s = 0; s < 4; ++s) {
            const int i = i0 + rl + 16 * s;
            const float val = (i >= UNIF_START) ? u : 0.0f;
            float4 v; v.x = v.y = v.z = v.w = val;
            *reinterpret_cast<float4*>(&att[(size_t)i * N_TOK + j0 + c4]) = v;
        }
        const ushort4 z = {0, 0, 0, 0};
#pragma unroll
        for (int s = 0; s < 4; ++s) {
            const int j = j0 + rl + 16 * s;
            *reinterpret_cast<ushort4*>(&attT[(size_t)j * N_TOK + i0 + c4]) = z;
        }
        return;
    }

    __shared__ unsigned short tile[64][72];
#pragma unroll
    for (int s = 0; s < 4; ++s) {
        const int il = rl + 16 * s;
        const int i  = i0 + il;
        const float inv = 1.0f / rowsum[i];
        float4 v = *reinterpret_cast<const float4*>(&att[(size_t)i * N_TOK + j0 + c4]);
        v.x *= inv; v.y *= inv; v.z *= inv; v.w *= inv;
        *reinterpret_cast<float4*>(&att[(size_t)i * N_TOK + j0 + c4]) = v;
        ushort4 b;
        if (i >= UNIF_START) {
            b.x = b.y = b.z = b.w = 0;    // folded into svec
        } else {
            b.x = f2bf(v.x); b.y = f2bf(v.y); b.z = f2bf(v.z); b.w = f2bf(v.w);
        }
        *reinterpret_cast<ushort4*>(&tile[il][c4]) = b;
    }
    __syncthreads();
#pragma unroll
    for (int s = 0; s < 4; ++s) {
        const int jl = rl + 16 * s;
        ushort4 o;
        o.x = tile[c4 + 0][jl];
        o.y = tile[c4 + 1][jl];
        o.z = tile[c4 + 2][jl];
        o.w = tile[c4 + 3][jl];
        *reinterpret_cast<ushort4*>(&attT[(size_t)(j0 + jl) * N_TOK + i0 + c4]) = o;
    }
}

extern "C" void kernel_launch(void* const* d_in, const int* in_sizes, int n_in,
                              void* d_out, int out_size, void* d_ws, size_t ws_size,
                              hipStream_t stream) {
    const float* x    = (const float*)d_in[0];
    const float* WK   = (const float*)d_in[1];
    const float* WQ   = (const float*)d_in[2];
    const float* WV   = (const float*)d_in[3];
    const float* Wout = (const float*)d_in[4];

    float* y   = (float*)d_out;                  // 4096 x 1024 fp32
    float* att = y + (size_t)N_TOK * M_DIM;      // 4096 x 4096 fp32 (E, then normalized)

    // ws layout (ushort elements); 1 MEG = 2 MB
    unsigned short* base = (unsigned short*)d_ws;
    const size_t MEG = 1u << 20;
    unsigned short* xb    = base;             // [0,4)   x bf16; later VWt
    unsigned short* WKt   = base + 4  * MEG;  // [4,5)
    unsigned short* WQt   = base + 5  * MEG;  // [5,6)
    unsigned short* Woutt = base + 6  * MEG;  // [6,7)
    unsigned short* WVb   = base + 7  * MEG;  // [7,8)
    unsigned short* WVWt  = base + 8  * MEG;  // [8,9)
    unsigned short* Kb    = base + 9  * MEG;  // [9,13)
    unsigned short* Qb    = base + 13 * MEG;  // [13,17)
    unsigned short* VWb   = base + 17 * MEG;  // [17,21)
    unsigned short* attT  = base + 4  * MEG;  // [4,20) overlays dead wgt/Kb/Qb/VWb[0..3M)
    float*          rowsum = (float*)(base + 20 * MEG); // 16 KB (after VWb read)
    float*          svec   = (float*)(base + 20 * MEG) + 4096; // 4 KB s-vector
    unsigned short* VWt   = xb;               // [0,4) overlays dead xb

    const dim3 blk(256);

    // 1) input casts / transposes (merged x+WV cast)
    cast2<<<dim3((N_TOK * M_DIM + M_DIM * M_DIM) / 1024), blk, 0, stream>>>(x, xb, WV, WVb);
    wtrans3<<<dim3(M_DIM / 32, M_DIM / 32, 3), blk, 0, stream>>>(WK, WQ, Wout, WKt, WQt, Woutt);

    // 2) WVW^T = Wout^T @ WV^T  (folds Wout into the V projection)
    nt64sq<<<dim3(M_DIM / 64, M_DIM / 64), blk, 0, stream>>>(Woutt, WVb, WVWt, M_DIM, M_DIM);

    // 3) fused K/Q/VW projections
    mfma_qkv<<<dim3(24, N_TOK / 128), blk, 0, stream>>>(xb, WKt, WQt, WVWt, Kb, Qb, VWb);

    // 4) VW^T (xb region is dead now); svec + rowsum init; y base rows
    transpose_bf16<<<dim3(M_DIM / 32, N_TOK / 32), blk, 0, stream>>>(VWb, VWt, N_TOK, M_DIM);
    prep_sr<<<dim3(20), blk, 0, stream>>>(VWb, svec, rowsum);
    init_y<<<dim3(512), blk, 0, stream>>>(y, svec);

    // 5) logits -> masked exp E + row sums (compact 465-block grid, BK=32 core)
    logits_128<<<dim3(465), blk, 0, stream>>>(Qb, Kb, att, rowsum);

    // 6) normalize att in place + build attT (bf16, uniform rows zeroed), fused
    finalize_att<<<dim3(N_TOK / 64, N_TOK / 64), blk, 0, stream>>>(att, attT, rowsum);

    // 7) y += attT(kept) @ VW  (R7/R9-verified atv_split, 704 blocks)
    atv_split<<<dim3(704), blk, 0, stream>>>(attT, VWt, y, svec);
}